// Round 5
// baseline (688.970 us; speedup 1.0000x reference)
//
#include <hip/hip_runtime.h>

// GRU (reset_after, inference) + dense head, fully fused. fp32 VALU design.
// B=1024 rows, T=512 steps, F=16, H=64.
//
// R0-R3 lesson: the AMDGPU RA consistently allocates ~88-96 arch VGPRs and
// sinks/spills any loop-invariant set that pushes the live set past that,
// regardless of __launch_bounds__ / amdgpu_waves_per_eu hints. So this
// version FITS UNDER the target instead of fighting it:
//   - 4 waves per block (256 thr); wave w owns k-quarter [16w,16w+16) and
//     f-quarter [4w,4w+4): U-frag 48 + W-frag 12 = 60 weight VGPRs/wave.
//   - (z,r) accumulators and their weights packed as float2 ->
//     v_pk_fma_f32 halves the z/r FMA issue count.
//   - total live set ~= 85 VGPRs -> no pressure, no reload.
// One barrier per step; partials combined via parity double-buffered LDS in
// a FIXED slot order so every wave computes bit-identical h (gates are
// computed redundantly per wave -> h available for next step's readlanes).
// x_t enters via wave-uniform s_load (readfirstlane'd quarter offset),
// prefetched one step ahead.

typedef float v2f __attribute__((ext_vector_type(2)));

#define T_ 512
#define F_ 16
#define H_ 64

__device__ __forceinline__ float sigm(float a) {
    return 1.0f / (1.0f + __expf(-a));
}
__device__ __forceinline__ float tanh_fast(float a) {
    // tanh(a) = 1 - 2/(exp(2a)+1); saturates correctly for large |a|
    return 1.0f - 2.0f / (__expf(2.0f * a) + 1.0f);
}

__global__ __launch_bounds__(256)
__attribute__((amdgpu_waves_per_eu(4, 4)))
void gru_fused(
    const float* __restrict__ x, const float* __restrict__ W,
    const float* __restrict__ U, const float* __restrict__ b,
    const float* __restrict__ w1, const float* __restrict__ b1,
    const float* __restrict__ gamma_, const float* __restrict__ beta_,
    const float* __restrict__ mmean, const float* __restrict__ mvar,
    const float* __restrict__ w2, const float* __restrict__ b2,
    float* __restrict__ out)
{
    __shared__ __align__(16) float comb[2 * 4 * 64 * 4];  // 8 KB: [parity][slot][lane][4]

    const int tid = threadIdx.x;
    const int j   = tid & 63;                         // hidden unit
    const int w   = tid >> 6;                         // wave 0..3
    const int row = blockIdx.x;
    const int wu  = __builtin_amdgcn_readfirstlane(w);
    const int k0  = wu * 16;                          // this wave's k-quarter
    const int f0  = wu * 4;                           // this wave's f-quarter

    // ---- weight fragments: 60 floats/wave ----
    v2f   uzr[16];   // {U_z[k][j], U_r[k][j]} packed
    float uh[16];
    #pragma unroll
    for (int k = 0; k < 16; ++k) {
        const float* Urow = U + (k0 + k) * 192;
        uzr[k] = (v2f){ Urow[j], Urow[64 + j] };
        uh[k]  = Urow[128 + j];
    }
    v2f   wzr[4];
    float wh[4];
    #pragma unroll
    for (int f = 0; f < 4; ++f) {
        const float* Wrow = W + (f0 + f) * 192;
        wzr[f] = (v2f){ Wrow[j], Wrow[64 + j] };
        wh[f]  = Wrow[128 + j];
    }

    // biases only in slot-0's partial (fixed-order combine keeps h identical)
    v2f   bzr = (v2f){ 0.f, 0.f };
    float bxh = 0.f, brh = 0.f;
    if (w == 0) {
        bzr = (v2f){ b[j] + b[192 + j],        // bi_z + br_z
                     b[64 + j] + b[256 + j] }; // bi_r + br_r
        bxh = b[128 + j];                      // bi_h (x-side)
        brh = b[320 + j];                      // br_h (rec-side)
    }

    // ---- wave-uniform x pointer; this wave's 4-float f-quarter per step ----
    const float4* xp = (const float4*)(x + (size_t)row * (T_ * F_));
    float4 xa = xp[wu];                        // x_0 quarter

    float h = 0.0f;
    for (int t = 0; t < T_; ++t) {
        // prefetch x_{t+1} quarter (uniform s_load, hidden behind FMAs)
        float4 xb;
        if (t + 1 < T_) xb = xp[(t + 1) * 4 + wu];

        v2f   azr = bzr;
        float axh = bxh, arh = brh;

        // input projection: 4 pk_fma + 4 fma
        {
            const float xv[4] = { xa.x, xa.y, xa.z, xa.w };
            #pragma unroll
            for (int f = 0; f < 4; ++f) {
                const v2f xs2 = (v2f){ xv[f], xv[f] };
                azr = __builtin_elementwise_fma(wzr[f], xs2, azr);
                axh = fmaf(xv[f], wh[f], axh);
            }
        }

        // recurrence k-quarter: 16 readlane + 16 pk_fma + 16 fma
        {
            const int hb = __float_as_int(h);
            #pragma unroll
            for (int k = 0; k < 16; ++k) {
                const float hk = __int_as_float(__builtin_amdgcn_readlane(hb, k0 + k));
                const v2f hk2 = (v2f){ hk, hk };
                azr = __builtin_elementwise_fma(uzr[k], hk2, azr);
                arh = fmaf(hk, uh[k], arh);
            }
        }

        // combine: write own partial, ONE barrier, sum all 4 slots in fixed order
        const int p = t & 1;
        *(float4*)&comb[((p * 4 + w) * 64 + j) * 4] =
            make_float4(azr.x, azr.y, axh, arh);
        __syncthreads();
        const float4* cb = (const float4*)&comb[(p * 4) * 64 * 4];
        const float4 s0 = cb[0 * 64 + j];
        const float4 s1 = cb[1 * 64 + j];
        const float4 s2 = cb[2 * 64 + j];
        const float4 s3 = cb[3 * 64 + j];
        const float az  = (s0.x + s1.x) + (s2.x + s3.x);
        const float ar_ = (s0.y + s1.y) + (s2.y + s3.y);
        const float xh  = (s0.z + s1.z) + (s2.z + s3.z);
        const float rh  = (s0.w + s1.w) + (s2.w + s3.w);

        // gates (redundant in all 4 waves; identical order -> identical bits)
        const float z  = sigm(az);
        const float r  = sigm(ar_);
        const float hh = tanh_fast(fmaf(r, rh, xh));
        h = fmaf(z, h - hh, hh);

        xa = xb;
    }

    // ---- head (wave 0 only): y=relu(h@w1+b1); BN; out=y@w2+b2 ----
    if (w == 0) {
        const int hb = __float_as_int(h);
        float y = b1[j];
        #pragma unroll 8
        for (int k = 0; k < H_; ++k) {
            const float hk = __int_as_float(__builtin_amdgcn_readlane(hb, k));
            y = fmaf(hk, w1[k * 64 + j], y);
        }
        y = fmaxf(y, 0.0f);
        y = fmaf((y - mmean[j]) * rsqrtf(mvar[j] + 1e-3f), gamma_[j], beta_[j]);

        float acc = y * w2[j];
        #pragma unroll
        for (int off = 32; off > 0; off >>= 1)
            acc += __shfl_down(acc, off, 64);
        if (j == 0) out[row] = acc + b2[0];
    }
}

extern "C" void kernel_launch(void* const* d_in, const int* in_sizes, int n_in,
                              void* d_out, int out_size, void* d_ws, size_t ws_size,
                              hipStream_t stream) {
    const float* x      = (const float*)d_in[0];
    const float* W      = (const float*)d_in[1];
    const float* U      = (const float*)d_in[2];
    const float* b      = (const float*)d_in[3];
    const float* w1     = (const float*)d_in[4];
    const float* b1     = (const float*)d_in[5];
    const float* gamma_ = (const float*)d_in[6];
    const float* beta_  = (const float*)d_in[7];
    const float* mmean  = (const float*)d_in[8];
    const float* mvar   = (const float*)d_in[9];
    const float* w2     = (const float*)d_in[10];
    const float* b2     = (const float*)d_in[11];
    float* out = (float*)d_out;

    const int B = in_sizes[0] / (T_ * F_);   // 1024
    gru_fused<<<B, 256, 0, stream>>>(x, W, U, b, w1, b1, gamma_, beta_,
                                     mmean, mvar, w2, b2, out);
}